// Round 22
// baseline (849.356 us; speedup 1.0000x reference)
//
#include <hip/hip_runtime.h>
#include <cstdint>
#include <cstddef>

#define NEG_INF (-3.402823466e38f)
typedef unsigned short u16;
typedef unsigned int u32;
typedef unsigned long long u64;

typedef short s16x8 __attribute__((ext_vector_type(8)));
typedef __bf16 bf16x8_t __attribute__((ext_vector_type(8)));
typedef float f32x4 __attribute__((ext_vector_type(4)));

__device__ __forceinline__ f32x4 mfma_bf16(s16x8 a, s16x8 b, f32x4 c){
    return __builtin_amdgcn_mfma_f32_16x16x32_bf16(
        __builtin_bit_cast(bf16x8_t, a), __builtin_bit_cast(bf16x8_t, b), c, 0, 0, 0);
}
__device__ __forceinline__ float b2f(u16 u){ return __uint_as_float(((u32)u) << 16); }
__device__ __forceinline__ u16 f2bu(float f){           // RNE fp32 -> bf16 bits
    u32 u = __float_as_uint(f);
    return (u16)((u + 0x7fffu + ((u >> 16) & 1u)) >> 16);
}
// async global->LDS, 16B/lane; LDS dest = wave-uniform base + lane*16 (m97 pattern)
__device__ __forceinline__ void gload16(const u16* __restrict__ g, u16* l){
    __builtin_amdgcn_global_load_lds(
        (const __attribute__((address_space(1))) u32*)g,
        (__attribute__((address_space(3))) u32*)l, 16, 0, 0);
}
// monotone (val desc, idx asc) <-> u64 key desc ; keys unique (idx unique), > 0
__device__ __forceinline__ u64 mkkey(float v, int id){
    u32 s = __float_as_uint(v);
    s ^= (u32)(((int)s >> 31)) | 0x80000000u;
    return ((u64)s << 32) | (u32)(~(u32)id);
}

// ---------------- top-k helpers (JAX lax.top_k stable: val desc, idx asc on ties) ----
__device__ __forceinline__ bool tk_gt(float v, int i, float w, int j){
    return (v > w) || (v == w && i < j);
}
__device__ __forceinline__ void tk_insert(float v, int id, float tv[3], int ti[3]){
    if (!tk_gt(v, id, tv[2], ti[2])) return;
    if (tk_gt(v, id, tv[1], ti[1])) {
        tv[2]=tv[1]; ti[2]=ti[1];
        if (tk_gt(v, id, tv[0], ti[0])) { tv[1]=tv[0]; ti[1]=ti[0]; tv[0]=v; ti[0]=id; }
        else { tv[1]=v; ti[1]=id; }
    } else { tv[2]=v; ti[2]=id; }
}

// ---------------- prep_all: all weight conversions in ONE launch --------------------
__device__ __forceinline__ void tc_tile(const float* in, int K, int N, u16* out,
                                        int bx, int by, int tid, float (*t)[33])
{
    const int kb = bx*32, nb = by*32;
    const int tx = tid & 31, ty = tid >> 5;
#pragma unroll
    for (int r=0;r<4;r++)
        t[ty + r*8][tx] = in[(size_t)(kb + ty + r*8)*N + nb + tx];
    __syncthreads();
#pragma unroll
    for (int r=0;r<4;r++)
        out[(size_t)(nb + ty + r*8)*K + kb + tx] = f2bu(t[tx][ty + r*8]);
}
__global__ __launch_bounds__(256)
void prep_all(const float* conv_w, u16* WbH, u16* WbL,
              const float* wl0, const float* wr0, const float* wl1, const float* wr1,
              const float* wl2, const float* wr2, const float* wl3, const float* wr3,
              u16* Wt0, u16* Wt1, u16* Wt2, u16* Wt3,
              const float* fc3_w, u16* WtF,
              const float* fc2_w, u16* W2h, u16* W2l)
{
    __shared__ float t[32][33];
    int b = blockIdx.x, tid = threadIdx.x;
    if (b < 1600) {                                   // conv_w split, flat float4
        int i = b*256 + tid;
        float4 v = ((const float4*)conv_w)[i];
        float f[4] = {v.x, v.y, v.z, v.w};
        u16 h[4], l[4];
#pragma unroll
        for (int j=0;j<4;j++){
            u16 hb = f2bu(f[j]);
            h[j] = hb;
            l[j] = f2bu(f[j] - b2f(hb));
        }
        *(ushort4*)&WbH[i*4] = *(ushort4*)h;
        *(ushort4*)&WbL[i*4] = *(ushort4*)l;
        return;
    }
    b -= 1600;
    if (b < 4096) {                                   // 8 projection transposes
        int m = b >> 9, tt = b & 511;
        const float* src[8] = {wl0, wr0, wl1, wr1, wl2, wr2, wl3, wr3};
        u16* Wt[4] = {Wt0, Wt1, Wt2, Wt3};
        int layer = m >> 1, half = m & 1;
        u16* dst = Wt[layer] + (size_t)half * 2048 * 256;
        if ((layer & 1) == 0)
            tc_tile(src[m], 256, 2048, dst, tt & 7, tt >> 3, tid, t);
        else
            tc_tile(src[m], 2048, 256, dst, tt & 63, tt >> 6, tid, t);
        return;
    }
    b -= 4096;
    if (b < 128) {                                    // fc3 (K=512, N=256): 16 x 8
        tc_tile(fc3_w, 512, 256, WtF, b & 15, b >> 4, tid, t);
        return;
    }
    b -= 128;                                         // fc2 hilo (K=256,N=256): 8 x 8
    {
        const int kb = (b & 7)*32, nb = (b >> 3)*32;
        const int tx = tid & 31, ty = tid >> 5;
#pragma unroll
        for (int r=0;r<4;r++)
            t[ty + r*8][tx] = fc2_w[(size_t)(kb + ty + r*8)*256 + nb + tx];
        __syncthreads();
#pragma unroll
        for (int r=0;r<4;r++){
            float v = t[tx][ty + r*8];
            u16 hb = f2bu(v);
            W2h[(size_t)(nb + ty + r*8)*256 + kb + tx] = hb;
            W2l[(size_t)(nb + ty + r*8)*256 + kb + tx] = f2bu(v - b2f(hb));
        }
    }
}

// im2col + bf16-split, READ-COALESCED. One block per (channel, patch-row).
__global__ __launch_bounds__(256)
void xpb_build(const float* __restrict__ x, int base,
               u16* __restrict__ xh, u16* __restrict__ xl)
{
    __shared__ u16 lh[96*26], ll[96*26];
    const int c = blockIdx.x / 48;
    const int piL = blockIdx.x - c*48;
    const int pi = (base/96) + piL;
    const int tid = threadIdx.x;

    for (int e = tid; e < 600; e += 256){
        int r = e / 120, col4 = e - r*120;
        float4 v = *(const float4*)(x + (size_t)c*230400 + (size_t)(pi*5+r)*480 + col4*4);
        float f[4] = {v.x, v.y, v.z, v.w};
#pragma unroll
        for (int j=0;j<4;j++){
            int col = col4*4 + j;
            int pj = col / 5, jj = col - pj*5;
            u16 hb = f2bu(f[j]);
            int lo = pj*26 + r*5 + jj;
            lh[lo] = hb;
            ll[lo] = f2bu(f[j] - b2f(hb));
        }
    }
    __syncthreads();
    for (int e = tid; e < 2400; e += 256){
        int pj = e / 25, kk = e - pj*25;
        size_t go = (size_t)(piL*96 + pj)*6400 + c*25 + kk;
        xh[go] = lh[pj*26 + kk];
        xl[go] = ll[pj*26 + kk];
    }
}

// sum 4 K-split partials + bias + relu -> emb1 as bf16 hi/lo (feeds fc2 MFMA)
__global__ void conv_reduce2(const float* __restrict__ p, const float* __restrict__ bias,
                             u16* __restrict__ oh, u16* __restrict__ ol)
{
    int i = blockIdx.x * 256 + threadIdx.x;
    const float4* p4 = (const float4*)p;
    float4 s = p4[i];
#pragma unroll
    for (int j=1;j<4;j++){
        float4 v = p4[i + (size_t)j*294912];
        s.x += v.x; s.y += v.y; s.z += v.z; s.w += v.w;
    }
    float4 bb = ((const float4*)bias)[i & 63];
    float f[4] = {fmaxf(s.x+bb.x,0.f), fmaxf(s.y+bb.y,0.f),
                  fmaxf(s.z+bb.z,0.f), fmaxf(s.w+bb.w,0.f)};
    u16 h[4], l[4];
#pragma unroll
    for (int j=0;j<4;j++){
        u16 hb = f2bu(f[j]);
        h[j] = hb;
        l[j] = f2bu(f[j] - b2f(hb));
    }
    *(ushort4*)&oh[i*4] = *(ushort4*)h;
    *(ushort4*)&ol[i*4] = *(ushort4*)l;
}

// ---------------- bf16 MFMA NT GEMM core: C[M][N] = A[M][K] @ B[N][K]^T ------------
// 128x128 tile, BK 32 or 64 (R22), global_load_lds staging, linear LDS [128][BK].
// BK=64 halves barrier/vmcnt-drain count per K (short-K prologue amortization);
// accumulation order k-ascending in both -> bit-identical. EPI as before.
template<bool SPLIT, int EPI, bool SWAPG, int BK>
__device__ __forceinline__
void mm_core(const u16* __restrict__ Ah, const u16* __restrict__ Al, int lda,
             const u16* __restrict__ Bh, const u16* __restrict__ Bl, int ldb,
             const float* __restrict__ bias0, const float* __restrict__ bias1, int nHalf,
             void* __restrict__ Cout, int ldc, int K,
             u64* __restrict__ apk, u16* __restrict__ Cout2)
{
    constexpr int TSZ = 128 * BK;
    __shared__ u16 smem[(SPLIT ? 4 : 2) * TSZ];
    u16* AsH = smem;
    u16* BsH = smem + TSZ;
    u16* AsL = SPLIT ? smem + 2*TSZ : nullptr;
    u16* BsL = SPLIT ? smem + 3*TSZ : nullptr;

    const int tid = threadIdx.x;
    const int w = tid >> 6, ln = tid & 63;
    const int wr = w >> 1, wc = w & 1;
    const int fr = ln & 15, fq = ln >> 4;
    const int mb = (SWAPG ? blockIdx.y : blockIdx.x) * 128;
    const int nb = (SWAPG ? blockIdx.x : blockIdx.y) * 128;

    int kbeg = 0;
    if constexpr (EPI == 2) kbeg = blockIdx.z * K;
    const int kend = kbeg + K;

    f32x4 acc[4][4];
#pragma unroll
    for (int i=0;i<4;i++)
#pragma unroll
        for (int j=0;j<4;j++) acc[i][j] = (f32x4){0.f,0.f,0.f,0.f};

    for (int k0 = kbeg; k0 < kend; k0 += BK) {
        if constexpr (BK == 32) {
#pragma unroll
            for (int t=0;t<2;t++){
                int rbase = w*32 + t*16;
                int r = rbase + (ln >> 2);
                size_t goA = (size_t)(mb + r)*lda + k0 + (ln & 3)*8;
                size_t goB = (size_t)(nb + r)*ldb + k0 + (ln & 3)*8;
                gload16(Ah + goA, AsH + rbase*32);
                gload16(Bh + goB, BsH + rbase*32);
                if constexpr (SPLIT){
                    gload16(Al + goA, AsL + rbase*32);
                    gload16(Bl + goB, BsL + rbase*32);
                }
            }
        } else {      // BK == 64: per instr 8 rows x 64 u16; lane l -> row l>>3, k (l&7)*8
#pragma unroll
            for (int t=0;t<4;t++){
                int rbase = w*32 + t*8;
                int r = rbase + (ln >> 3);
                size_t goA = (size_t)(mb + r)*lda + k0 + (ln & 7)*8;
                size_t goB = (size_t)(nb + r)*ldb + k0 + (ln & 7)*8;
                gload16(Ah + goA, AsH + rbase*64);
                gload16(Bh + goB, BsH + rbase*64);
                if constexpr (SPLIT){
                    gload16(Al + goA, AsL + rbase*64);
                    gload16(Bl + goB, BsL + rbase*64);
                }
            }
        }
        __syncthreads();
#pragma unroll
        for (int h=0; h<BK/32; h++){
            s16x8 ah[4], bh[4], al[4], bl[4];
#pragma unroll
            for (int mi=0;mi<4;mi++){
                int ro = (wr*64 + mi*16 + fr)*BK + h*32 + fq*8;
                ah[mi] = *(const s16x8*)&AsH[ro];
                if constexpr (SPLIT) al[mi] = *(const s16x8*)&AsL[ro];
            }
#pragma unroll
            for (int nj=0;nj<4;nj++){
                int ro = (wc*64 + nj*16 + fr)*BK + h*32 + fq*8;
                bh[nj] = *(const s16x8*)&BsH[ro];
                if constexpr (SPLIT) bl[nj] = *(const s16x8*)&BsL[ro];
            }
#pragma unroll
            for (int mi=0;mi<4;mi++)
#pragma unroll
                for (int nj=0;nj<4;nj++){
                    acc[mi][nj] = mfma_bf16(ah[mi], bh[nj], acc[mi][nj]);
                    if constexpr (SPLIT){
                        acc[mi][nj] = mfma_bf16(ah[mi], bl[nj], acc[mi][nj]);
                        acc[mi][nj] = mfma_bf16(al[mi], bh[nj], acc[mi][nj]);
                    }
                }
        }
        __syncthreads();
    }

    if constexpr (EPI == 0) {
        u16* ldsc = smem;
#pragma unroll
        for (int chunk=0; chunk<4; ++chunk){
            __syncthreads();
            if (wr == (chunk>>1)){
                int mi0 = (chunk&1)*2;
#pragma unroll
                for (int m2=0;m2<2;m2++){
                    int mi = mi0 + m2;
#pragma unroll
                    for (int nj=0;nj<4;nj++)
#pragma unroll
                    for (int t=0;t<4;t++){
                        int lr = m2*16 + fq*4 + t;
                        int lc = wc*64 + nj*16 + fr;
                        int col = nb + lc;
                        float v = acc[mi][nj][t];
                        if (bias0) v += (col < nHalf) ? bias0[col] : bias1[col - nHalf];
                        ldsc[lr*136 + lc] = f2bu(v);
                    }
                }
            }
            __syncthreads();
            int c0 = chunk*32;
#pragma unroll
            for (int q=0;q<2;q++){
                int e = q*256 + tid;
                int lr = e >> 4, c16 = e & 15;
                *(uint4*)((u16*)Cout + (size_t)(mb + c0 + lr)*ldc + nb + c16*8)
                    = *(const uint4*)&ldsc[lr*136 + c16*8];
            }
        }
    } else if constexpr (EPI == 2 || EPI == 3 || EPI == 4) {
        float* ldsf = (float*)smem;
        const int NC = (EPI == 2) ? 256 : ldc;
#pragma unroll
        for (int chunk=0; chunk<8; ++chunk){
            __syncthreads();
            if (wr == (chunk>>2)){
                int mi = chunk & 3;
#pragma unroll
                for (int nj=0;nj<4;nj++)
#pragma unroll
                for (int t=0;t<4;t++){
                    int lr = fq*4 + t;
                    int lc = wc*64 + nj*16 + fr;
                    float v = acc[mi][nj][t];
                    if constexpr (EPI == 3 || EPI == 4){
                        v += bias0[nb + lc];
                        v = fmaxf(v, 0.f);
                    }
                    ldsf[lr*132 + lc] = v;
                }
            }
            __syncthreads();
            int c0 = chunk*16;
#pragma unroll
            for (int q=0;q<2;q++){
                int e = q*256 + tid;
                int lr = e >> 5, c4 = e & 31;
                int row = mb + c0 + lr, col = nb + c4*4;
                if constexpr (EPI == 3){
                    float4 a = *(const float4*)(bias1 + (size_t)row*NC + col);
                    float4 v = *(const float4*)&ldsf[lr*132 + c4*4];
                    v.x += a.x; v.y += a.y; v.z += a.z; v.w += a.w;
                    *(float4*)((float*)Cout + (size_t)row*NC + col) = v;
                } else if constexpr (EPI == 4){
                    float4 v = *(const float4*)&ldsf[lr*132 + c4*4];
                    *(float4*)((float*)Cout + (size_t)row*NC + col) = v;
                    u16 hh[4] = {f2bu(v.x), f2bu(v.y), f2bu(v.z), f2bu(v.w)};
                    *(uint2*)(Cout2 + (size_t)row*NC + col) = *(uint2*)hh;
                } else {
                    *(float4*)((float*)Cout + ((size_t)blockIdx.z*4608 + row)*256 + col)
                        = *(const float4*)&ldsf[lr*132 + c4*4];
                }
            }
        }
    } else {
        // swapped-selection: adj row = B-side (nb + wc*64 + nj*16 + fr); c = A-side.
        const int cbR = blockIdx.x * 2 + wr;
#pragma unroll
        for (int nj=0;nj<4;nj++){
            int row = nb + wc*64 + nj*16 + fr;
            float tv[3] = {NEG_INF, NEG_INF, NEG_INF};
            int   ti[3] = {0x7fffffff, 0x7fffffff, 0x7fffffff};
#pragma unroll
            for (int mi=0;mi<4;mi++)
#pragma unroll
                for (int t=0;t<4;t++)
                    tk_insert(acc[mi][nj][t], mb + wr*64 + mi*16 + fq*4 + t, tv, ti);
#pragma unroll
            for (int off=16; off<64; off<<=1){
                float ov[3]; int oi[3];
#pragma unroll
                for (int e=0;e<3;e++){ ov[e]=__shfl_xor(tv[e],off); oi[e]=__shfl_xor(ti[e],off); }
#pragma unroll
                for (int e=0;e<3;e++) tk_insert(ov[e], oi[e], tv, ti);
            }
            if (fq == 0){
#pragma unroll
                for (int e=0;e<3;e++)
                    apk[(size_t)row*432 + cbR*3 + e] = mkkey(tv[e], ti[e]);
            }
        }
    }
}

// named instantiations (distinct rocprof rows); BK=64 on non-split GEMMs (R22)
__global__ __launch_bounds__(256)
void mm_proj(const u16* Ah, int lda, const u16* Bh, int ldb,
             const float* bias0, const float* bias1, int nHalf,
             void* Cout, int ldc, int K)
{
    mm_core<false,0,false,64>(Ah, nullptr, lda, Bh, nullptr, ldb, bias0, bias1, nHalf,
                              Cout, ldc, K, nullptr, nullptr);
}
__global__ __launch_bounds__(256)
void mm_projT(const u16* Ah, int lda, const u16* Bh, int ldb,
              const float* bias0, const float* bias1, int nHalf,
              void* Cout, int ldc, int K)
{
    mm_core<false,0,true,64>(Ah, nullptr, lda, Bh, nullptr, ldb, bias0, bias1, nHalf,
                             Cout, ldc, K, nullptr, nullptr);
}
__global__ __launch_bounds__(256)
void mm_adj(const u16* Ah, int lda, u64* apk)
{
    mm_core<false,1,false,64>(Ah, nullptr, lda, Ah, nullptr, lda, nullptr, nullptr, 0,
                              nullptr, 0, 256, apk, nullptr);
}
__global__ __launch_bounds__(256)
void mm_conv(const u16* Ah, const u16* Al, int lda, const u16* Bh, const u16* Bl, int ldb,
             float* Cout, int K)
{
    mm_core<true,2,false,32>(Ah, Al, lda, Bh, Bl, ldb, nullptr, nullptr, 0,
                             Cout, 256, K, nullptr, nullptr);
}
// fc2: emb = relu(emb1 @ W2t^T + b), split-bf16 3-term; dual out f32 + bf16
__global__ __launch_bounds__(256)
void mm_fc2(const u16* Ah, const u16* Al, const u16* Bh, const u16* Bl,
            const float* bias, float* Cout, u16* Cout2)
{
    mm_core<true,4,false,32>(Ah, Al, 256, Bh, Bl, 256, bias, nullptr, 0,
                             Cout, 256, 256, nullptr, Cout2);
}
// fc3: out = relu(hcat @ WtF^T + bias) + add ; f32 out, ld 256
__global__ __launch_bounds__(256)
void mm_fc3(const u16* Ah, int lda, const u16* Bh, int ldb,
            const float* bias, const float* add, float* Cout)
{
    mm_core<false,3,false,64>(Ah, nullptr, lda, Bh, nullptr, ldb, bias, add, 0,
                              Cout, 256, 512, nullptr, nullptr);
}

// fused merge+rescore: 432 packed keys/row -> top-8 -> exact fp32 rescore -> top-3.
__device__ __forceinline__ void ce_desc(u64& a, u64& b){
    u64 mx = a > b ? a : b; u64 mn = a > b ? b : a; a = mx; b = mn;
}
__global__ __launch_bounds__(256)
void adj_select(const u64* __restrict__ apk, const float* __restrict__ emb,
                float* __restrict__ vals, int* __restrict__ idx)
{
    int row = blockIdx.x * 4 + (threadIdx.x >> 6);
    int ln = threadIdx.x & 63;
    u64 k[7];
#pragma unroll
    for (int j=0;j<7;j++){
        int t = ln + 64*j;
        k[j] = (t < 432) ? apk[(size_t)row*432 + t] : 0ull;
    }
    ce_desc(k[0],k[6]); ce_desc(k[2],k[3]); ce_desc(k[4],k[5]);
    ce_desc(k[0],k[2]); ce_desc(k[1],k[4]); ce_desc(k[3],k[6]);
    ce_desc(k[0],k[1]); ce_desc(k[2],k[5]); ce_desc(k[3],k[4]);
    ce_desc(k[1],k[2]); ce_desc(k[4],k[6]);
    ce_desc(k[2],k[3]); ce_desc(k[4],k[5]);
    ce_desc(k[1],k[2]); ce_desc(k[3],k[4]); ce_desc(k[5],k[6]);
    int cand[8];
#pragma unroll
    for (int r=0;r<8;r++){
        u64 m = k[0];
#pragma unroll
        for (int off=1; off<64; off<<=1){
            u64 o = __shfl_xor((unsigned long long)m, off);
            m = o > m ? o : m;
        }
        if (k[0] == m){
            k[0]=k[1]; k[1]=k[2]; k[2]=k[3]; k[3]=k[4]; k[4]=k[5]; k[5]=k[6]; k[6]=0ull;
        }
        cand[r] = (int)(~(u32)(m & 0xFFFFFFFFull));
    }
    float a[4];
    *(float4*)a = *(const float4*)(emb + (size_t)row*256 + ln*4);
    float sc[8];
#pragma unroll
    for (int c=0;c<8;c++){
        float4 bb = *(const float4*)(emb + (size_t)cand[c]*256 + ln*4);
        float p = a[0]*bb.x + a[1]*bb.y + a[2]*bb.z + a[3]*bb.w;
#pragma unroll
        for (int off=1; off<64; off<<=1) p += __shfl_xor(p, off);
        sc[c] = p;
    }
    if (ln == 0){
        float tv[3]={NEG_INF,NEG_INF,NEG_INF};
        int   ti[3]={0x7fffffff,0x7fffffff,0x7fffffff};
#pragma unroll
        for (int c=0;c<8;c++) tk_insert(sc[c], cand[c], tv, ti);
#pragma unroll
        for (int e=0;e<3;e++){ vals[row*3+e]=tv[e]; idx[row*3+e]=ti[e]; }
    }
}

// ---------------- GATv2 softmax + aggregate + bias + ELU, bf16 inputs --------------
template<int H, int TPH, bool SPATIAL>
__global__ __launch_bounds__(H*TPH)
void gat_agg(const u16* __restrict__ xlxr, int ldx, int xrOff,
             const float* __restrict__ att, const float* __restrict__ bias,
             const float* __restrict__ vals, const int* __restrict__ idx,
             u16* __restrict__ outp, int ldo,
             float* __restrict__ out2, int ldo2)
{
    constexpr int D = 256;
    constexpr int DPT = D / TPH;
    const int n = blockIdx.x;
    const int tid = threadIdx.x;
    const int h = tid / TPH;
    const int l = tid % TPH;
    const int d0 = l * DPT;

    int srcs[4]; bool valid[4];
#pragma unroll
    for (int s=0;s<4;s++){ srcs[s]=n; valid[s]=(s==3); }
    if constexpr (SPATIAL) {
        int pi = n / 96, pj = n - (n/96)*96;
        int cand[4]; int nc=0;
        if (pi > 0)  cand[nc++] = n - 96;
        if (pj > 0)  cand[nc++] = n - 1;
        if (pj < 95) cand[nc++] = n + 1;
        if (pi < 95) cand[nc++] = n + 96;
        int s0 = cand[0], s1 = cand[1];
        if (s0 > n){ srcs[0]=s0; valid[0]=true; }
        if (s1 > n){ srcs[1]=s1; valid[1]=true; }
    } else {
#pragma unroll
        for (int t=0;t<3;t++){
            int s = idx[n*3+t];
            float v = vals[n*3+t];
            if (s > n && v != 0.0f){ srcs[t]=s; valid[t]=true; }
        }
    }

    float xrv[DPT], attv[DPT];
#pragma unroll
    for (int q=0;q<DPT/4;q++){
        ushort4 u = *(const ushort4*)(xlxr + (size_t)n*ldx + xrOff + h*D + d0 + q*4);
        xrv[q*4+0]=b2f(u.x); xrv[q*4+1]=b2f(u.y); xrv[q*4+2]=b2f(u.z); xrv[q*4+3]=b2f(u.w);
        *(float4*)&attv[q*4] = *(const float4*)(att + h*D + d0 + q*4);
    }

    float xs[4][DPT];
    float sc[4];
#pragma unroll
    for (int s=0;s<4;s++){
#pragma unroll
        for (int q=0;q<DPT/4;q++){
            ushort4 u = *(const ushort4*)(xlxr + (size_t)srcs[s]*ldx + h*D + d0 + q*4);
            xs[s][q*4+0]=b2f(u.x); xs[s][q*4+1]=b2f(u.y); xs[s][q*4+2]=b2f(u.z); xs[s][q*4+3]=b2f(u.w);
        }
        float p = 0.f;
#pragma unroll
        for (int d=0;d<DPT;d++){
            float e = xs[s][d] + xrv[d];
            e = (e > 0.f) ? e : 0.2f*e;
            p += attv[d]*e;
        }
#pragma unroll
        for (int off=1; off<TPH; off<<=1) p += __shfl_xor(p, off);
        sc[s] = p;
    }
    float m = NEG_INF;
#pragma unroll
    for (int s=0;s<4;s++) if (valid[s]) m = fmaxf(m, sc[s]);
    float al[4]; float denom = 0.f;
#pragma unroll
    for (int s=0;s<4;s++){ al[s] = valid[s] ? expf(sc[s]-m) : 0.f; denom += al[s]; }
    float inv = 1.f / denom;

    float o[DPT];
#pragma unroll
    for (int d=0;d<DPT;d++){
        float acc = al[0]*xs[0][d] + al[1]*xs[1][d] + al[2]*xs[2][d] + al[3]*xs[3][d];
        acc = acc*inv + bias[h*D + d0 + d];
        o[d] = (acc > 0.f) ? acc : (expf(acc) - 1.f);
    }
    u16 ov[DPT];
#pragma unroll
    for (int d=0;d<DPT;d++) ov[d] = f2bu(o[d]);
    if constexpr (DPT >= 8){
#pragma unroll
        for (int q=0;q<DPT/8;q++)
            *(uint4*)(outp + (size_t)n*ldo + h*D + d0 + q*8) = *(uint4*)&ov[q*8];
    } else {
        *(uint2*)(outp + (size_t)n*ldo + h*D + d0) = *(uint2*)ov;
    }
    if (out2){
#pragma unroll
        for (int q=0;q<DPT/4;q++)
            *(float4*)(out2 + (size_t)n*ldo2 + h*D + d0 + q*4) = *(float4*)&o[q*4];
    }
}

// ---------------------------------------------------------------------------
extern "C" void kernel_launch(void* const* d_in, const int* in_sizes, int n_in,
                              void* d_out, int out_size, void* d_ws, size_t ws_size,
                              hipStream_t stream)
{
    (void)in_sizes; (void)n_in;
    const float* x      = (const float*)d_in[0];
    const float* conv_w = (const float*)d_in[1];
    const float* conv_b = (const float*)d_in[2];
    const float* fc2_w  = (const float*)d_in[3];
    const float* fc2_b  = (const float*)d_in[4];
    const float* fc3_w  = (const float*)d_in[5];
    const float* fc3_b  = (const float*)d_in[6];
    const float* g_wl[4]   = {(const float*)d_in[7],  (const float*)d_in[13], (const float*)d_in[19], (const float*)d_in[25]};
    const float* g_bl[4]   = {(const float*)d_in[8],  (const float*)d_in[14], (const float*)d_in[20], (const float*)d_in[26]};
    const float* g_wr[4]   = {(const float*)d_in[9],  (const float*)d_in[15], (const float*)d_in[21], (const float*)d_in[27]};
    const float* g_br[4]   = {(const float*)d_in[10], (const float*)d_in[16], (const float*)d_in[22], (const float*)d_in[28]};
    const float* g_att[4]  = {(const float*)d_in[11], (const float*)d_in[17], (const float*)d_in[23], (const float*)d_in[29]};
    const float* g_bias[4] = {(const float*)d_in[12], (const float*)d_in[18], (const float*)d_in[24], (const float*)d_in[30]};

    float* ws = (float*)d_ws;
    size_t off = 0;
    // persistent (never aliased): e1h/e1l
    u16*   e1h  = (u16*)(ws + off); off += 1179648;           // [9216][256] bf16 hi
    u16*   e1l  = (u16*)(ws + off); off += 1179648;           // [9216][256] bf16 lo
    // ALIASED REGION (conv scratch lives here; all these buffers written POST-conv)
    size_t emb_off = off;
    float* emb   = ws + off; off += 2359296;                  // written by fc2
    u16*   emb_h = (u16*)(ws + off); off += 1179648;          // written by fc2
    u64*   apk  = (u64*)(ws + off); off += 7962624;           // written by mm_adj
    float* vals = ws + off; off += 27648;                     // written by adj_select
    int*   idx  = (int*)(ws + off); off += 27648;
    u16*   hcat = (u16*)(ws + off); off += 2359296;           // written by gat_agg g2/g4
    float* h4   = ws + off; off += 2359296;                   // written by gat_agg g4
    u16*   xlxr = (u16*)(ws + off); off += 18874368;          // written by mm_proj
    u16*   hbig = (u16*)(ws + off); off += 9437184;           // written by gat_agg g1/g3
    // TAIL (never aliased): all weight buffers — prep_all runs BEFORE conv
    u16*   Wt[4];
    Wt[0] = (u16*)(ws + off); off += 524288;                  // [4096][256] bf16
    Wt[1] = (u16*)(ws + off); off += 524288;                  // [512][2048] bf16
    Wt[2] = (u16*)(ws + off); off += 524288;
    Wt[3] = (u16*)(ws + off); off += 524288;
    u16*   WtF  = (u16*)(ws + off); off += 65536;             // [256][512] bf16 (fc3)
    u16*   W2h  = (u16*)(ws + off); off += 32768;             // [256][256] bf16 (fc2 hi)
    u16*   W2l  = (u16*)(ws + off); off += 32768;             // [256][256] bf16 (fc2 lo)
    u16*   WbH  = (u16*)(ws + off); off += 851968;            // [256][6400] bf16 (conv W)
    u16*   WbL  = (u16*)(ws + off); off += 851968;
    // conv-phase scratch aliased onto the aliased region (touches NO weight buffer)
    u16*   xp_h = (u16*)(ws + emb_off);                          // [4608][6400] u16
    u16*   xp_l = (u16*)(ws + emb_off + 14745600);
    float* cpart = ws + emb_off + 29491200;                      // [4][4608][256] f32
    size_t need = off * sizeof(float);
    if (ws_size < need) {
        hipMemsetAsync(d_out, 0, (size_t)out_size*sizeof(float), stream);
        return;
    }
    float* out = (float*)d_out;

    // all weight prep in one launch (targets tail buffers only)
    prep_all<<<5888,256,0,stream>>>(conv_w, WbH, WbL,
                                    g_wl[0], g_wr[0], g_wl[1], g_wr[1],
                                    g_wl[2], g_wr[2], g_wl[3], g_wr[3],
                                    Wt[0], Wt[1], Wt[2], Wt[3],
                                    fc3_w, WtF, fc2_w, W2h, W2l);
    // conv1 = bf16-split-3-term NT GEMM over im2col'd x (two row-halves, K-split x4)
    for (int half = 0; half < 2; ++half) {
        xpb_build<<<12288,256,0,stream>>>(x, half*4608, xp_h, xp_l);
        mm_conv<<<dim3(36,2,4),256,0,stream>>>(xp_h, xp_l, 6400, WbH, WbL, 6400, cpart, 1600);
        conv_reduce2<<<1152,256,0,stream>>>(cpart, conv_b,
                                            e1h + (size_t)half*4608*256,
                                            e1l + (size_t)half*4608*256);
    }
    // fc2 via split-bf16 MFMA -> emb f32 + emb_h bf16 (dual out)
    mm_fc2<<<dim3(72,2),256,0,stream>>>(e1h, e1l, W2h, W2l, fc2_b, emb, emb_h);

    // similarity kNN: candidates -> fused merge+rescore -> top-3
    mm_adj<<<dim3(72,72),256,0,stream>>>(emb_h, 256, apk);
    adj_select<<<2304,256,0,stream>>>(apk, emb, vals, idx);

    // g1 (H=8, similarity graph)
    mm_proj<<<dim3(72,32),256,0,stream>>>(emb_h, 256, Wt[0], 256, g_bl[0], g_br[0], 2048,
                                          xlxr, 4096, 256);
    gat_agg<8,32,false><<<9216,256,0,stream>>>(xlxr, 4096, 2048, g_att[0], g_bias[0], vals, idx,
                                               hbig, 2048, nullptr, 0);
    // g2 (H=1) -> hcat cols 0..255 ; n-fastest grid (hbig slab L2 reuse)
    mm_projT<<<dim3(4,72),256,0,stream>>>(hbig, 2048, Wt[1], 2048, g_bl[1], g_br[1], 256,
                                          xlxr, 512, 2048);
    gat_agg<1,64,false><<<9216,64,0,stream>>>(xlxr, 512, 256, g_att[1], g_bias[1], vals, idx,
                                              hcat, 512, nullptr, 0);
    // g3 (H=8, spatial graph)
    mm_proj<<<dim3(72,32),256,0,stream>>>(emb_h, 256, Wt[2], 256, g_bl[2], g_br[2], 2048,
                                          xlxr, 4096, 256);
    gat_agg<8,32,true><<<9216,256,0,stream>>>(xlxr, 4096, 2048, g_att[2], g_bias[2], nullptr, nullptr,
                                              hbig, 2048, nullptr, 0);
    // g4 (H=1) -> hcat cols 256..511 + h4 f32 (exact residual)
    mm_projT<<<dim3(4,72),256,0,stream>>>(hbig, 2048, Wt[3], 2048, g_bl[3], g_br[3], 256,
                                          xlxr, 512, 2048);
    gat_agg<1,64,true><<<9216,64,0,stream>>>(xlxr, 512, 256, g_att[3], g_bias[3], nullptr, nullptr,
                                             hcat + 256, 512, h4, 256);

    // fc3 via bf16 MFMA: out = relu(hcat @ WtF^T + b) + h4
    mm_fc3<<<dim3(72,2),256,0,stream>>>(hcat, 512, WtF, 512, fc3_b, h4, out);
}

// Round 23
// 803.953 us; speedup vs baseline: 1.0565x; 1.0565x over previous
//
#include <hip/hip_runtime.h>
#include <cstdint>
#include <cstddef>

#define NEG_INF (-3.402823466e38f)
typedef unsigned short u16;
typedef unsigned int u32;
typedef unsigned long long u64;

typedef short s16x8 __attribute__((ext_vector_type(8)));
typedef __bf16 bf16x8_t __attribute__((ext_vector_type(8)));
typedef float f32x4 __attribute__((ext_vector_type(4)));

__device__ __forceinline__ f32x4 mfma_bf16(s16x8 a, s16x8 b, f32x4 c){
    return __builtin_amdgcn_mfma_f32_16x16x32_bf16(
        __builtin_bit_cast(bf16x8_t, a), __builtin_bit_cast(bf16x8_t, b), c, 0, 0, 0);
}
__device__ __forceinline__ float b2f(u16 u){ return __uint_as_float(((u32)u) << 16); }
__device__ __forceinline__ u16 f2bu(float f){           // RNE fp32 -> bf16 bits
    u32 u = __float_as_uint(f);
    return (u16)((u + 0x7fffu + ((u >> 16) & 1u)) >> 16);
}
// async global->LDS, 16B/lane; LDS dest = wave-uniform base + lane*16 (m97 pattern)
__device__ __forceinline__ void gload16(const u16* __restrict__ g, u16* l){
    __builtin_amdgcn_global_load_lds(
        (const __attribute__((address_space(1))) u32*)g,
        (__attribute__((address_space(3))) u32*)l, 16, 0, 0);
}
// monotone (val desc, idx asc) <-> u64 key desc ; keys unique (idx unique), > 0
__device__ __forceinline__ u64 mkkey(float v, int id){
    u32 s = __float_as_uint(v);
    s ^= (u32)(((int)s >> 31)) | 0x80000000u;
    return ((u64)s << 32) | (u32)(~(u32)id);
}

// ---------------- top-k helpers (JAX lax.top_k stable: val desc, idx asc on ties) ----
__device__ __forceinline__ bool tk_gt(float v, int i, float w, int j){
    return (v > w) || (v == w && i < j);
}
__device__ __forceinline__ void tk_insert(float v, int id, float tv[3], int ti[3]){
    if (!tk_gt(v, id, tv[2], ti[2])) return;
    if (tk_gt(v, id, tv[1], ti[1])) {
        tv[2]=tv[1]; ti[2]=ti[1];
        if (tk_gt(v, id, tv[0], ti[0])) { tv[1]=tv[0]; ti[1]=ti[0]; tv[0]=v; ti[0]=id; }
        else { tv[1]=v; ti[1]=id; }
    } else { tv[2]=v; ti[2]=id; }
}

// ---------------- prep_all: all weight conversions in ONE launch --------------------
__device__ __forceinline__ void tc_tile(const float* in, int K, int N, u16* out,
                                        int bx, int by, int tid, float (*t)[33])
{
    const int kb = bx*32, nb = by*32;
    const int tx = tid & 31, ty = tid >> 5;
#pragma unroll
    for (int r=0;r<4;r++)
        t[ty + r*8][tx] = in[(size_t)(kb + ty + r*8)*N + nb + tx];
    __syncthreads();
#pragma unroll
    for (int r=0;r<4;r++)
        out[(size_t)(nb + ty + r*8)*K + kb + tx] = f2bu(t[tx][ty + r*8]);
}
__global__ __launch_bounds__(256)
void prep_all(const float* conv_w, u16* WbH, u16* WbL,
              const float* wl0, const float* wr0, const float* wl1, const float* wr1,
              const float* wl2, const float* wr2, const float* wl3, const float* wr3,
              u16* Wt0, u16* Wt1, u16* Wt2, u16* Wt3,
              const float* fc3_w, u16* WtF,
              const float* fc2_w, u16* W2h, u16* W2l)
{
    __shared__ float t[32][33];
    int b = blockIdx.x, tid = threadIdx.x;
    if (b < 1600) {                                   // conv_w split, flat float4
        int i = b*256 + tid;
        float4 v = ((const float4*)conv_w)[i];
        float f[4] = {v.x, v.y, v.z, v.w};
        u16 h[4], l[4];
#pragma unroll
        for (int j=0;j<4;j++){
            u16 hb = f2bu(f[j]);
            h[j] = hb;
            l[j] = f2bu(f[j] - b2f(hb));
        }
        *(ushort4*)&WbH[i*4] = *(ushort4*)h;
        *(ushort4*)&WbL[i*4] = *(ushort4*)l;
        return;
    }
    b -= 1600;
    if (b < 4096) {                                   // 8 projection transposes
        int m = b >> 9, tt = b & 511;
        const float* src[8] = {wl0, wr0, wl1, wr1, wl2, wr2, wl3, wr3};
        u16* Wt[4] = {Wt0, Wt1, Wt2, Wt3};
        int layer = m >> 1, half = m & 1;
        u16* dst = Wt[layer] + (size_t)half * 2048 * 256;
        if ((layer & 1) == 0)
            tc_tile(src[m], 256, 2048, dst, tt & 7, tt >> 3, tid, t);
        else
            tc_tile(src[m], 2048, 256, dst, tt & 63, tt >> 6, tid, t);
        return;
    }
    b -= 4096;
    if (b < 128) {                                    // fc3 (K=512, N=256): 16 x 8
        tc_tile(fc3_w, 512, 256, WtF, b & 15, b >> 4, tid, t);
        return;
    }
    b -= 128;                                         // fc2 hilo (K=256,N=256): 8 x 8
    {
        const int kb = (b & 7)*32, nb = (b >> 3)*32;
        const int tx = tid & 31, ty = tid >> 5;
#pragma unroll
        for (int r=0;r<4;r++)
            t[ty + r*8][tx] = fc2_w[(size_t)(kb + ty + r*8)*256 + nb + tx];
        __syncthreads();
#pragma unroll
        for (int r=0;r<4;r++){
            float v = t[tx][ty + r*8];
            u16 hb = f2bu(v);
            W2h[(size_t)(nb + ty + r*8)*256 + kb + tx] = hb;
            W2l[(size_t)(nb + ty + r*8)*256 + kb + tx] = f2bu(v - b2f(hb));
        }
    }
}

// im2col + bf16-split, READ-COALESCED. One block per (channel, patch-row).
__global__ __launch_bounds__(256)
void xpb_build(const float* __restrict__ x, int base,
               u16* __restrict__ xh, u16* __restrict__ xl)
{
    __shared__ u16 lh[96*26], ll[96*26];
    const int c = blockIdx.x / 48;
    const int piL = blockIdx.x - c*48;
    const int pi = (base/96) + piL;
    const int tid = threadIdx.x;

    for (int e = tid; e < 600; e += 256){
        int r = e / 120, col4 = e - r*120;
        float4 v = *(const float4*)(x + (size_t)c*230400 + (size_t)(pi*5+r)*480 + col4*4);
        float f[4] = {v.x, v.y, v.z, v.w};
#pragma unroll
        for (int j=0;j<4;j++){
            int col = col4*4 + j;
            int pj = col / 5, jj = col - pj*5;
            u16 hb = f2bu(f[j]);
            int lo = pj*26 + r*5 + jj;
            lh[lo] = hb;
            ll[lo] = f2bu(f[j] - b2f(hb));
        }
    }
    __syncthreads();
    for (int e = tid; e < 2400; e += 256){
        int pj = e / 25, kk = e - pj*25;
        size_t go = (size_t)(piL*96 + pj)*6400 + c*25 + kk;
        xh[go] = lh[pj*26 + kk];
        xl[go] = ll[pj*26 + kk];
    }
}

// sum 4 K-split partials + bias + relu -> emb1 as bf16 hi/lo (feeds fc2 MFMA)
__global__ void conv_reduce2(const float* __restrict__ p, const float* __restrict__ bias,
                             u16* __restrict__ oh, u16* __restrict__ ol)
{
    int i = blockIdx.x * 256 + threadIdx.x;
    const float4* p4 = (const float4*)p;
    float4 s = p4[i];
#pragma unroll
    for (int j=1;j<4;j++){
        float4 v = p4[i + (size_t)j*294912];
        s.x += v.x; s.y += v.y; s.z += v.z; s.w += v.w;
    }
    float4 bb = ((const float4*)bias)[i & 63];
    float f[4] = {fmaxf(s.x+bb.x,0.f), fmaxf(s.y+bb.y,0.f),
                  fmaxf(s.z+bb.z,0.f), fmaxf(s.w+bb.w,0.f)};
    u16 h[4], l[4];
#pragma unroll
    for (int j=0;j<4;j++){
        u16 hb = f2bu(f[j]);
        h[j] = hb;
        l[j] = f2bu(f[j] - b2f(hb));
    }
    *(ushort4*)&oh[i*4] = *(ushort4*)h;
    *(ushort4*)&ol[i*4] = *(ushort4*)l;
}

// ---------------- bf16 MFMA NT GEMM core: C[M][N] = A[M][K] @ B[N][K]^T ------------
// 128x128 tile, BK=32, global_load_lds staging, linear LDS [128][32].
// EPI 0: bf16 store. EPI 1: swapped-operand top-3 packed keys. EPI 2: conv K-split
// f32 partials. EPI 3: f32 relu(acc+bias)+add (fc3). EPI 4: f32 relu(acc+bias) and
// bf16 dual-store (fc2). SWAPG: n-tile fast (A-slab L2 reuse).
template<bool SPLIT, int EPI, bool SWAPG>
__device__ __forceinline__
void mm_core(const u16* __restrict__ Ah, const u16* __restrict__ Al, int lda,
             const u16* __restrict__ Bh, const u16* __restrict__ Bl, int ldb,
             const float* __restrict__ bias0, const float* __restrict__ bias1, int nHalf,
             void* __restrict__ Cout, int ldc, int K,
             u64* __restrict__ apk, u16* __restrict__ Cout2)
{
    constexpr int TSZ = 128 * 32;
    __shared__ u16 smem[(SPLIT ? 4 : 2) * TSZ];
    u16* AsH = smem;
    u16* BsH = smem + TSZ;
    u16* AsL = SPLIT ? smem + 2*TSZ : nullptr;
    u16* BsL = SPLIT ? smem + 3*TSZ : nullptr;

    const int tid = threadIdx.x;
    const int w = tid >> 6, ln = tid & 63;
    const int wr = w >> 1, wc = w & 1;
    const int fr = ln & 15, fq = ln >> 4;
    const int mb = (SWAPG ? blockIdx.y : blockIdx.x) * 128;
    const int nb = (SWAPG ? blockIdx.x : blockIdx.y) * 128;
    const int skk = (ln & 3) * 8;

    int kbeg = 0;
    if constexpr (EPI == 2) kbeg = blockIdx.z * K;
    const int kend = kbeg + K;

    f32x4 acc[4][4];
#pragma unroll
    for (int i=0;i<4;i++)
#pragma unroll
        for (int j=0;j<4;j++) acc[i][j] = (f32x4){0.f,0.f,0.f,0.f};

    for (int k0 = kbeg; k0 < kend; k0 += 32) {
#pragma unroll
        for (int t=0;t<2;t++){
            int rbase = w*32 + t*16;
            int r = rbase + (ln >> 2);
            size_t goA = (size_t)(mb + r)*lda + k0 + skk;
            size_t goB = (size_t)(nb + r)*ldb + k0 + skk;
            gload16(Ah + goA, AsH + rbase*32);
            gload16(Bh + goB, BsH + rbase*32);
            if constexpr (SPLIT){
                gload16(Al + goA, AsL + rbase*32);
                gload16(Bl + goB, BsL + rbase*32);
            }
        }
        __syncthreads();
        s16x8 ah[4], bh[4], al[4], bl[4];
#pragma unroll
        for (int mi=0;mi<4;mi++){
            int ro = (wr*64 + mi*16 + fr)*32 + fq*8;
            ah[mi] = *(const s16x8*)&AsH[ro];
            if constexpr (SPLIT) al[mi] = *(const s16x8*)&AsL[ro];
        }
#pragma unroll
        for (int nj=0;nj<4;nj++){
            int ro = (wc*64 + nj*16 + fr)*32 + fq*8;
            bh[nj] = *(const s16x8*)&BsH[ro];
            if constexpr (SPLIT) bl[nj] = *(const s16x8*)&BsL[ro];
        }
#pragma unroll
        for (int mi=0;mi<4;mi++)
#pragma unroll
            for (int nj=0;nj<4;nj++){
                acc[mi][nj] = mfma_bf16(ah[mi], bh[nj], acc[mi][nj]);
                if constexpr (SPLIT){
                    acc[mi][nj] = mfma_bf16(ah[mi], bl[nj], acc[mi][nj]);
                    acc[mi][nj] = mfma_bf16(al[mi], bh[nj], acc[mi][nj]);
                }
            }
        __syncthreads();
    }

    if constexpr (EPI == 0) {
        u16* ldsc = smem;
#pragma unroll
        for (int chunk=0; chunk<4; ++chunk){
            __syncthreads();
            if (wr == (chunk>>1)){
                int mi0 = (chunk&1)*2;
#pragma unroll
                for (int m2=0;m2<2;m2++){
                    int mi = mi0 + m2;
#pragma unroll
                    for (int nj=0;nj<4;nj++)
#pragma unroll
                    for (int t=0;t<4;t++){
                        int lr = m2*16 + fq*4 + t;
                        int lc = wc*64 + nj*16 + fr;
                        int col = nb + lc;
                        float v = acc[mi][nj][t];
                        if (bias0) v += (col < nHalf) ? bias0[col] : bias1[col - nHalf];
                        ldsc[lr*136 + lc] = f2bu(v);
                    }
                }
            }
            __syncthreads();
            int c0 = chunk*32;
#pragma unroll
            for (int q=0;q<2;q++){
                int e = q*256 + tid;
                int lr = e >> 4, c16 = e & 15;
                *(uint4*)((u16*)Cout + (size_t)(mb + c0 + lr)*ldc + nb + c16*8)
                    = *(const uint4*)&ldsc[lr*136 + c16*8];
            }
        }
    } else if constexpr (EPI == 2 || EPI == 3 || EPI == 4) {
        float* ldsf = (float*)smem;
        const int NC = (EPI == 2) ? 256 : ldc;
#pragma unroll
        for (int chunk=0; chunk<8; ++chunk){
            __syncthreads();
            if (wr == (chunk>>2)){
                int mi = chunk & 3;
#pragma unroll
                for (int nj=0;nj<4;nj++)
#pragma unroll
                for (int t=0;t<4;t++){
                    int lr = fq*4 + t;
                    int lc = wc*64 + nj*16 + fr;
                    float v = acc[mi][nj][t];
                    if constexpr (EPI == 3 || EPI == 4){
                        v += bias0[nb + lc];
                        v = fmaxf(v, 0.f);
                    }
                    ldsf[lr*132 + lc] = v;
                }
            }
            __syncthreads();
            int c0 = chunk*16;
#pragma unroll
            for (int q=0;q<2;q++){
                int e = q*256 + tid;
                int lr = e >> 5, c4 = e & 31;
                int row = mb + c0 + lr, col = nb + c4*4;
                if constexpr (EPI == 3){
                    float4 a = *(const float4*)(bias1 + (size_t)row*NC + col);
                    float4 v = *(const float4*)&ldsf[lr*132 + c4*4];
                    v.x += a.x; v.y += a.y; v.z += a.z; v.w += a.w;
                    *(float4*)((float*)Cout + (size_t)row*NC + col) = v;
                } else if constexpr (EPI == 4){
                    float4 v = *(const float4*)&ldsf[lr*132 + c4*4];
                    *(float4*)((float*)Cout + (size_t)row*NC + col) = v;
                    u16 hh[4] = {f2bu(v.x), f2bu(v.y), f2bu(v.z), f2bu(v.w)};
                    *(uint2*)(Cout2 + (size_t)row*NC + col) = *(uint2*)hh;
                } else {
                    *(float4*)((float*)Cout + ((size_t)blockIdx.z*4608 + row)*256 + col)
                        = *(const float4*)&ldsf[lr*132 + c4*4];
                }
            }
        }
    } else {
        // swapped-selection: adj row = B-side (nb + wc*64 + nj*16 + fr); c = A-side.
        const int cbR = blockIdx.x * 2 + wr;
#pragma unroll
        for (int nj=0;nj<4;nj++){
            int row = nb + wc*64 + nj*16 + fr;
            float tv[3] = {NEG_INF, NEG_INF, NEG_INF};
            int   ti[3] = {0x7fffffff, 0x7fffffff, 0x7fffffff};
#pragma unroll
            for (int mi=0;mi<4;mi++)
#pragma unroll
                for (int t=0;t<4;t++)
                    tk_insert(acc[mi][nj][t], mb + wr*64 + mi*16 + fq*4 + t, tv, ti);
#pragma unroll
            for (int off=16; off<64; off<<=1){
                float ov[3]; int oi[3];
#pragma unroll
                for (int e=0;e<3;e++){ ov[e]=__shfl_xor(tv[e],off); oi[e]=__shfl_xor(ti[e],off); }
#pragma unroll
                for (int e=0;e<3;e++) tk_insert(ov[e], oi[e], tv, ti);
            }
            if (fq == 0){
#pragma unroll
                for (int e=0;e<3;e++)
                    apk[(size_t)row*432 + cbR*3 + e] = mkkey(tv[e], ti[e]);
            }
        }
    }
}

// named instantiations (distinct rocprof rows)
__global__ __launch_bounds__(256)
void mm_proj(const u16* Ah, int lda, const u16* Bh, int ldb,
             const float* bias0, const float* bias1, int nHalf,
             void* Cout, int ldc, int K)
{
    mm_core<false,0,false>(Ah, nullptr, lda, Bh, nullptr, ldb, bias0, bias1, nHalf,
                           Cout, ldc, K, nullptr, nullptr);
}
__global__ __launch_bounds__(256)
void mm_projT(const u16* Ah, int lda, const u16* Bh, int ldb,
              const float* bias0, const float* bias1, int nHalf,
              void* Cout, int ldc, int K)
{
    mm_core<false,0,true>(Ah, nullptr, lda, Bh, nullptr, ldb, bias0, bias1, nHalf,
                          Cout, ldc, K, nullptr, nullptr);
}
__global__ __launch_bounds__(256)
void mm_adj(const u16* Ah, int lda, u64* apk)
{
    mm_core<false,1,false>(Ah, nullptr, lda, Ah, nullptr, lda, nullptr, nullptr, 0,
                           nullptr, 0, 256, apk, nullptr);
}
__global__ __launch_bounds__(256)
void mm_conv(const u16* Ah, const u16* Al, int lda, const u16* Bh, const u16* Bl, int ldb,
             float* Cout, int K)
{
    mm_core<true,2,false>(Ah, Al, lda, Bh, Bl, ldb, nullptr, nullptr, 0,
                          Cout, 256, K, nullptr, nullptr);
}
// fc2: emb = relu(emb1 @ W2t^T + b), split-bf16 3-term; dual out f32 + bf16
__global__ __launch_bounds__(256)
void mm_fc2(const u16* Ah, const u16* Al, const u16* Bh, const u16* Bl,
            const float* bias, float* Cout, u16* Cout2)
{
    mm_core<true,4,false>(Ah, Al, 256, Bh, Bl, 256, bias, nullptr, 0,
                          Cout, 256, 256, nullptr, Cout2);
}
// fc3: out = relu(hcat @ WtF^T + bias) + add ; f32 out, ld 256
__global__ __launch_bounds__(256)
void mm_fc3(const u16* Ah, int lda, const u16* Bh, int ldb,
            const float* bias, const float* add, float* Cout)
{
    mm_core<false,3,false>(Ah, nullptr, lda, Bh, nullptr, ldb, bias, add, 0,
                           Cout, 256, 512, nullptr, nullptr);
}

// fused merge+rescore: 432 packed keys/row -> top-8 -> exact fp32 rescore -> top-3.
__device__ __forceinline__ void ce_desc(u64& a, u64& b){
    u64 mx = a > b ? a : b; u64 mn = a > b ? b : a; a = mx; b = mn;
}
__global__ __launch_bounds__(256)
void adj_select(const u64* __restrict__ apk, const float* __restrict__ emb,
                float* __restrict__ vals, int* __restrict__ idx)
{
    int row = blockIdx.x * 4 + (threadIdx.x >> 6);
    int ln = threadIdx.x & 63;
    u64 k[7];
#pragma unroll
    for (int j=0;j<7;j++){
        int t = ln + 64*j;
        k[j] = (t < 432) ? apk[(size_t)row*432 + t] : 0ull;
    }
    ce_desc(k[0],k[6]); ce_desc(k[2],k[3]); ce_desc(k[4],k[5]);
    ce_desc(k[0],k[2]); ce_desc(k[1],k[4]); ce_desc(k[3],k[6]);
    ce_desc(k[0],k[1]); ce_desc(k[2],k[5]); ce_desc(k[3],k[4]);
    ce_desc(k[1],k[2]); ce_desc(k[4],k[6]);
    ce_desc(k[2],k[3]); ce_desc(k[4],k[5]);
    ce_desc(k[1],k[2]); ce_desc(k[3],k[4]); ce_desc(k[5],k[6]);
    int cand[8];
#pragma unroll
    for (int r=0;r<8;r++){
        u64 m = k[0];
#pragma unroll
        for (int off=1; off<64; off<<=1){
            u64 o = __shfl_xor((unsigned long long)m, off);
            m = o > m ? o : m;
        }
        if (k[0] == m){
            k[0]=k[1]; k[1]=k[2]; k[2]=k[3]; k[3]=k[4]; k[4]=k[5]; k[5]=k[6]; k[6]=0ull;
        }
        cand[r] = (int)(~(u32)(m & 0xFFFFFFFFull));
    }
    float a[4];
    *(float4*)a = *(const float4*)(emb + (size_t)row*256 + ln*4);
    float sc[8];
#pragma unroll
    for (int c=0;c<8;c++){
        float4 bb = *(const float4*)(emb + (size_t)cand[c]*256 + ln*4);
        float p = a[0]*bb.x + a[1]*bb.y + a[2]*bb.z + a[3]*bb.w;
#pragma unroll
        for (int off=1; off<64; off<<=1) p += __shfl_xor(p, off);
        sc[c] = p;
    }
    if (ln == 0){
        float tv[3]={NEG_INF,NEG_INF,NEG_INF};
        int   ti[3]={0x7fffffff,0x7fffffff,0x7fffffff};
#pragma unroll
        for (int c=0;c<8;c++) tk_insert(sc[c], cand[c], tv, ti);
#pragma unroll
        for (int e=0;e<3;e++){ vals[row*3+e]=tv[e]; idx[row*3+e]=ti[e]; }
    }
}

// ---------------- GATv2 softmax + aggregate + bias + ELU, bf16 inputs --------------
template<int H, int TPH, bool SPATIAL>
__global__ __launch_bounds__(H*TPH)
void gat_agg(const u16* __restrict__ xlxr, int ldx, int xrOff,
             const float* __restrict__ att, const float* __restrict__ bias,
             const float* __restrict__ vals, const int* __restrict__ idx,
             u16* __restrict__ outp, int ldo,
             float* __restrict__ out2, int ldo2)
{
    constexpr int D = 256;
    constexpr int DPT = D / TPH;
    const int n = blockIdx.x;
    const int tid = threadIdx.x;
    const int h = tid / TPH;
    const int l = tid % TPH;
    const int d0 = l * DPT;

    int srcs[4]; bool valid[4];
#pragma unroll
    for (int s=0;s<4;s++){ srcs[s]=n; valid[s]=(s==3); }
    if constexpr (SPATIAL) {
        int pi = n / 96, pj = n - (n/96)*96;
        int cand[4]; int nc=0;
        if (pi > 0)  cand[nc++] = n - 96;
        if (pj > 0)  cand[nc++] = n - 1;
        if (pj < 95) cand[nc++] = n + 1;
        if (pi < 95) cand[nc++] = n + 96;
        int s0 = cand[0], s1 = cand[1];
        if (s0 > n){ srcs[0]=s0; valid[0]=true; }
        if (s1 > n){ srcs[1]=s1; valid[1]=true; }
    } else {
#pragma unroll
        for (int t=0;t<3;t++){
            int s = idx[n*3+t];
            float v = vals[n*3+t];
            if (s > n && v != 0.0f){ srcs[t]=s; valid[t]=true; }
        }
    }

    float xrv[DPT], attv[DPT];
#pragma unroll
    for (int q=0;q<DPT/4;q++){
        ushort4 u = *(const ushort4*)(xlxr + (size_t)n*ldx + xrOff + h*D + d0 + q*4);
        xrv[q*4+0]=b2f(u.x); xrv[q*4+1]=b2f(u.y); xrv[q*4+2]=b2f(u.z); xrv[q*4+3]=b2f(u.w);
        *(float4*)&attv[q*4] = *(const float4*)(att + h*D + d0 + q*4);
    }

    float xs[4][DPT];
    float sc[4];
#pragma unroll
    for (int s=0;s<4;s++){
#pragma unroll
        for (int q=0;q<DPT/4;q++){
            ushort4 u = *(const ushort4*)(xlxr + (size_t)srcs[s]*ldx + h*D + d0 + q*4);
            xs[s][q*4+0]=b2f(u.x); xs[s][q*4+1]=b2f(u.y); xs[s][q*4+2]=b2f(u.z); xs[s][q*4+3]=b2f(u.w);
        }
        float p = 0.f;
#pragma unroll
        for (int d=0;d<DPT;d++){
            float e = xs[s][d] + xrv[d];
            e = (e > 0.f) ? e : 0.2f*e;
            p += attv[d]*e;
        }
#pragma unroll
        for (int off=1; off<TPH; off<<=1) p += __shfl_xor(p, off);
        sc[s] = p;
    }
    float m = NEG_INF;
#pragma unroll
    for (int s=0;s<4;s++) if (valid[s]) m = fmaxf(m, sc[s]);
    float al[4]; float denom = 0.f;
#pragma unroll
    for (int s=0;s<4;s++){ al[s] = valid[s] ? expf(sc[s]-m) : 0.f; denom += al[s]; }
    float inv = 1.f / denom;

    float o[DPT];
#pragma unroll
    for (int d=0;d<DPT;d++){
        float acc = al[0]*xs[0][d] + al[1]*xs[1][d] + al[2]*xs[2][d] + al[3]*xs[3][d];
        acc = acc*inv + bias[h*D + d0 + d];
        o[d] = (acc > 0.f) ? acc : (expf(acc) - 1.f);
    }
    u16 ov[DPT];
#pragma unroll
    for (int d=0;d<DPT;d++) ov[d] = f2bu(o[d]);
    if constexpr (DPT >= 8){
#pragma unroll
        for (int q=0;q<DPT/8;q++)
            *(uint4*)(outp + (size_t)n*ldo + h*D + d0 + q*8) = *(uint4*)&ov[q*8];
    } else {
        *(uint2*)(outp + (size_t)n*ldo + h*D + d0) = *(uint2*)ov;
    }
    if (out2){
#pragma unroll
        for (int q=0;q<DPT/4;q++)
            *(float4*)(out2 + (size_t)n*ldo2 + h*D + d0 + q*4) = *(float4*)&o[q*4];
    }
}

// ---------------------------------------------------------------------------
extern "C" void kernel_launch(void* const* d_in, const int* in_sizes, int n_in,
                              void* d_out, int out_size, void* d_ws, size_t ws_size,
                              hipStream_t stream)
{
    (void)in_sizes; (void)n_in;
    const float* x      = (const float*)d_in[0];
    const float* conv_w = (const float*)d_in[1];
    const float* conv_b = (const float*)d_in[2];
    const float* fc2_w  = (const float*)d_in[3];
    const float* fc2_b  = (const float*)d_in[4];
    const float* fc3_w  = (const float*)d_in[5];
    const float* fc3_b  = (const float*)d_in[6];
    const float* g_wl[4]   = {(const float*)d_in[7],  (const float*)d_in[13], (const float*)d_in[19], (const float*)d_in[25]};
    const float* g_bl[4]   = {(const float*)d_in[8],  (const float*)d_in[14], (const float*)d_in[20], (const float*)d_in[26]};
    const float* g_wr[4]   = {(const float*)d_in[9],  (const float*)d_in[15], (const float*)d_in[21], (const float*)d_in[27]};
    const float* g_br[4]   = {(const float*)d_in[10], (const float*)d_in[16], (const float*)d_in[22], (const float*)d_in[28]};
    const float* g_att[4]  = {(const float*)d_in[11], (const float*)d_in[17], (const float*)d_in[23], (const float*)d_in[29]};
    const float* g_bias[4] = {(const float*)d_in[12], (const float*)d_in[18], (const float*)d_in[24], (const float*)d_in[30]};

    float* ws = (float*)d_ws;
    size_t off = 0;
    // persistent (never aliased): e1h/e1l
    u16*   e1h  = (u16*)(ws + off); off += 1179648;           // [9216][256] bf16 hi
    u16*   e1l  = (u16*)(ws + off); off += 1179648;           // [9216][256] bf16 lo
    // ALIASED REGION (conv scratch lives here; all these buffers written POST-conv)
    size_t emb_off = off;
    float* emb   = ws + off; off += 2359296;                  // written by fc2
    u16*   emb_h = (u16*)(ws + off); off += 1179648;          // written by fc2
    u64*   apk  = (u64*)(ws + off); off += 7962624;           // written by mm_adj
    float* vals = ws + off; off += 27648;                     // written by adj_select
    int*   idx  = (int*)(ws + off); off += 27648;
    u16*   hcat = (u16*)(ws + off); off += 2359296;           // written by gat_agg g2/g4
    float* h4   = ws + off; off += 2359296;                   // written by gat_agg g4
    u16*   xlxr = (u16*)(ws + off); off += 18874368;          // written by mm_proj
    u16*   hbig = (u16*)(ws + off); off += 9437184;           // written by gat_agg g1/g3
    // TAIL (never aliased): all weight buffers — prep_all runs BEFORE conv
    u16*   Wt[4];
    Wt[0] = (u16*)(ws + off); off += 524288;                  // [4096][256] bf16
    Wt[1] = (u16*)(ws + off); off += 524288;                  // [512][2048] bf16
    Wt[2] = (u16*)(ws + off); off += 524288;
    Wt[3] = (u16*)(ws + off); off += 524288;
    u16*   WtF  = (u16*)(ws + off); off += 65536;             // [256][512] bf16 (fc3)
    u16*   W2h  = (u16*)(ws + off); off += 32768;             // [256][256] bf16 (fc2 hi)
    u16*   W2l  = (u16*)(ws + off); off += 32768;             // [256][256] bf16 (fc2 lo)
    u16*   WbH  = (u16*)(ws + off); off += 851968;            // [256][6400] bf16 (conv W)
    u16*   WbL  = (u16*)(ws + off); off += 851968;
    // conv-phase scratch aliased onto the aliased region (touches NO weight buffer)
    u16*   xp_h = (u16*)(ws + emb_off);                          // [4608][6400] u16
    u16*   xp_l = (u16*)(ws + emb_off + 14745600);
    float* cpart = ws + emb_off + 29491200;                      // [4][4608][256] f32
    size_t need = off * sizeof(float);
    if (ws_size < need) {
        hipMemsetAsync(d_out, 0, (size_t)out_size*sizeof(float), stream);
        return;
    }
    float* out = (float*)d_out;

    // all weight prep in one launch (targets tail buffers only)
    prep_all<<<5888,256,0,stream>>>(conv_w, WbH, WbL,
                                    g_wl[0], g_wr[0], g_wl[1], g_wr[1],
                                    g_wl[2], g_wr[2], g_wl[3], g_wr[3],
                                    Wt[0], Wt[1], Wt[2], Wt[3],
                                    fc3_w, WtF, fc2_w, W2h, W2l);
    // conv1 = bf16-split-3-term NT GEMM over im2col'd x (two row-halves, K-split x4)
    for (int half = 0; half < 2; ++half) {
        xpb_build<<<12288,256,0,stream>>>(x, half*4608, xp_h, xp_l);
        mm_conv<<<dim3(36,2,4),256,0,stream>>>(xp_h, xp_l, 6400, WbH, WbL, 6400, cpart, 1600);
        conv_reduce2<<<1152,256,0,stream>>>(cpart, conv_b,
                                            e1h + (size_t)half*4608*256,
                                            e1l + (size_t)half*4608*256);
    }
    // fc2 via split-bf16 MFMA -> emb f32 + emb_h bf16 (dual out)
    mm_fc2<<<dim3(72,2),256,0,stream>>>(e1h, e1l, W2h, W2l, fc2_b, emb, emb_h);

    // similarity kNN: candidates -> fused merge+rescore -> top-3
    mm_adj<<<dim3(72,72),256,0,stream>>>(emb_h, 256, apk);
    adj_select<<<2304,256,0,stream>>>(apk, emb, vals, idx);

    // g1 (H=8, similarity graph)
    mm_proj<<<dim3(72,32),256,0,stream>>>(emb_h, 256, Wt[0], 256, g_bl[0], g_br[0], 2048,
                                          xlxr, 4096, 256);
    gat_agg<8,32,false><<<9216,256,0,stream>>>(xlxr, 4096, 2048, g_att[0], g_bias[0], vals, idx,
                                               hbig, 2048, nullptr, 0);
    // g2 (H=1) -> hcat cols 0..255 ; n-fastest grid (hbig slab L2 reuse)
    mm_projT<<<dim3(4,72),256,0,stream>>>(hbig, 2048, Wt[1], 2048, g_bl[1], g_br[1], 256,
                                          xlxr, 512, 2048);
    gat_agg<1,64,false><<<9216,64,0,stream>>>(xlxr, 512, 256, g_att[1], g_bias[1], vals, idx,
                                              hcat, 512, nullptr, 0);
    // g3 (H=8, spatial graph)
    mm_proj<<<dim3(72,32),256,0,stream>>>(emb_h, 256, Wt[2], 256, g_bl[2], g_br[2], 2048,
                                          xlxr, 4096, 256);
    gat_agg<8,32,true><<<9216,256,0,stream>>>(xlxr, 4096, 2048, g_att[2], g_bias[2], nullptr, nullptr,
                                              hbig, 2048, nullptr, 0);
    // g4 (H=1) -> hcat cols 256..511 + h4 f32 (exact residual)
    mm_projT<<<dim3(4,72),256,0,stream>>>(hbig, 2048, Wt[3], 2048, g_bl[3], g_br[3], 256,
                                          xlxr, 512, 2048);
    gat_agg<1,64,true><<<9216,64,0,stream>>>(xlxr, 512, 256, g_att[3], g_bias[3], nullptr, nullptr,
                                             hcat + 256, 512, h4, 256);

    // fc3 via bf16 MFMA: out = relu(hcat @ WtF^T + b) + h4
    mm_fc3<<<dim3(72,2),256,0,stream>>>(hcat, 512, WtF, 512, fc3_b, h4, out);
}